// Round 1
// baseline (3629.548 us; speedup 1.0000x reference)
//
#include <hip/hip_runtime.h>

#define EMB 64
#define NLAYERS 3

// ---------------- degree: deg[col[e]] += 1 ----------------
__global__ void deg_kernel(const int* __restrict__ col, int* __restrict__ deg, int E) {
    int gid = blockIdx.x * blockDim.x + threadIdx.x;
    if (gid < E) atomicAdd(&deg[col[gid]], 1);
}

// ---------------- dis[i] = deg>0 ? rsqrt(deg) : 0 ----------------
__global__ void dis_kernel(const int* __restrict__ deg, float* __restrict__ dis, int N) {
    int gid = blockIdx.x * blockDim.x + threadIdx.x;
    if (gid < N) {
        int d = deg[gid];
        dis[gid] = (d > 0) ? rsqrtf((float)d) : 0.0f;
    }
}

// ---------------- init: acc = x = concat(user,movie); out(total) = x ----------------
__global__ void init_kernel(const float* __restrict__ ue, const float* __restrict__ me,
                            float* __restrict__ acc, float* __restrict__ out,
                            long long n_user_elems, long long total_elems) {
    long long gid = (long long)blockIdx.x * blockDim.x + threadIdx.x;
    if (gid < total_elems) {
        float v = (gid < n_user_elems) ? ue[gid] : me[gid - n_user_elems];
        acc[gid] = v;
        out[gid] = v;
    }
}

// ---------------- scatter: accB[col] += accA[row] * dis[row]*dis[col] ----------------
// one wave (64 lanes) per edge; lane d owns dim d. row[e]/col[e] are
// wave-uniform loads (hardware broadcast); gather is a coalesced 256B read.
__global__ void scatter_kernel(const int* __restrict__ row, const int* __restrict__ col,
                               const float* __restrict__ dis,
                               const float* __restrict__ accA, float* __restrict__ accB,
                               int E) {
    long long gid = (long long)blockIdx.x * blockDim.x + threadIdx.x;
    int e = (int)(gid >> 6);
    int d = (int)(gid & 63);
    if (e < E) {
        int r = row[e];
        int c = col[e];
        float nrm = dis[r] * dis[c];
        float v = accA[(long long)r * EMB + d] * nrm;
        atomicAdd(&accB[(long long)c * EMB + d], v);
    }
}

// ---------------- total accumulate (+ optional final scale) ----------------
__global__ void add_kernel(float* __restrict__ out, const float* __restrict__ acc,
                           float scale, long long n) {
    long long gid = (long long)blockIdx.x * blockDim.x + threadIdx.x;
    if (gid < n) out[gid] = (out[gid] + acc[gid]) * scale;
}

extern "C" void kernel_launch(void* const* d_in, const int* in_sizes, int n_in,
                              void* d_out, int out_size, void* d_ws, size_t ws_size,
                              hipStream_t stream) {
    const int*   edge = (const int*)d_in[0];    // [2, E] row-major: row then col
    const float* ue   = (const float*)d_in[2];  // [n_users, 64]
    const float* me   = (const float*)d_in[3];  // [n_movies, 64]
    float*       out  = (float*)d_out;          // [N, 64] (users then movies, flat)

    const int E        = in_sizes[0] / 2;
    const int n_users  = in_sizes[2] / EMB;
    const int n_movies = in_sizes[3] / EMB;
    const int N        = n_users + n_movies;
    const int* row = edge;
    const int* col = edge + E;

    // workspace layout (256B aligned slices)
    char* ws = (char*)d_ws;
    auto align_up = [](size_t v) { return (v + 255) & ~(size_t)255; };
    int*   deg  = (int*)ws;   ws += align_up((size_t)N * sizeof(int));
    float* dis  = (float*)ws; ws += align_up((size_t)N * sizeof(float));
    float* accA = (float*)ws; ws += align_up((size_t)N * EMB * sizeof(float));
    float* accB = (float*)ws; ws += align_up((size_t)N * EMB * sizeof(float));

    const long long total_elems = (long long)N * EMB;
    const long long user_elems  = (long long)n_users * EMB;

    // degree + normalization
    hipMemsetAsync(deg, 0, (size_t)N * sizeof(int), stream);
    deg_kernel<<<(E + 255) / 256, 256, 0, stream>>>(col, deg, E);
    dis_kernel<<<(N + 255) / 256, 256, 0, stream>>>(deg, dis, N);

    // acc0 = x, total = x
    init_kernel<<<(int)((total_elems + 255) / 256), 256, 0, stream>>>(
        ue, me, accA, out, user_elems, total_elems);

    // 3 propagation layers
    for (int l = 0; l < NLAYERS; ++l) {
        hipMemsetAsync(accB, 0, (size_t)N * EMB * sizeof(float), stream);
        long long sthreads = (long long)E * EMB;
        scatter_kernel<<<(int)((sthreads + 255) / 256), 256, 0, stream>>>(
            row, col, dis, accA, accB, E);
        float scale = (l == NLAYERS - 1) ? 1.0f / (NLAYERS + 1) : 1.0f;
        add_kernel<<<(int)((total_elems + 255) / 256), 256, 0, stream>>>(
            out, accB, scale, total_elems);
        float* t = accA; accA = accB; accB = t;
    }
}

// Round 2
// 1440.595 us; speedup vs baseline: 2.5195x; 2.5195x over previous
//
#include <hip/hip_runtime.h>

#define EMB 64
#define NLAYERS 3
#define SCAN_B 256

// ---------------- degree: deg[col[e]] += 1 ----------------
__global__ void deg_kernel(const int* __restrict__ col, int* __restrict__ deg, int E) {
    int gid = blockIdx.x * blockDim.x + threadIdx.x;
    if (gid < E) atomicAdd(&deg[col[gid]], 1);
}

// ---------------- dis[i] = deg>0 ? rsqrt(deg) : 0 ----------------
__global__ void dis_kernel(const int* __restrict__ deg, float* __restrict__ dis, int N) {
    int gid = blockIdx.x * blockDim.x + threadIdx.x;
    if (gid < N) {
        int d = deg[gid];
        dis[gid] = (d > 0) ? rsqrtf((float)d) : 0.0f;
    }
}

// ---------------- init: acc = x = concat(user,movie); out(total) = x ----------------
__global__ void init_kernel(const float* __restrict__ ue, const float* __restrict__ me,
                            float* __restrict__ acc, float* __restrict__ out,
                            long long n_user_elems, long long total_elems) {
    long long gid = (long long)blockIdx.x * blockDim.x + threadIdx.x;
    if (gid < total_elems) {
        float v = (gid < n_user_elems) ? ue[gid] : me[gid - n_user_elems];
        acc[gid] = v;
        out[gid] = v;
    }
}

// ---------------- CSR build: block-level exclusive scan of deg ----------------
__global__ void scan_block(const int* __restrict__ deg, int* __restrict__ start,
                           int* __restrict__ bsum, int N) {
    __shared__ int tmp[SCAN_B];
    int i = blockIdx.x * SCAN_B + threadIdx.x;
    int v = (i < N) ? deg[i] : 0;
    tmp[threadIdx.x] = v;
    __syncthreads();
    for (int off = 1; off < SCAN_B; off <<= 1) {
        int t = (threadIdx.x >= off) ? tmp[threadIdx.x - off] : 0;
        __syncthreads();
        tmp[threadIdx.x] += t;
        __syncthreads();
    }
    if (i < N) start[i] = tmp[threadIdx.x] - v;  // exclusive within block
    if (threadIdx.x == SCAN_B - 1) bsum[blockIdx.x] = tmp[threadIdx.x];
}

__global__ void scan_partials(int* __restrict__ bsum, int nb) {
    __shared__ int tmp[1024];
    int v = ((int)threadIdx.x < nb) ? bsum[threadIdx.x] : 0;
    tmp[threadIdx.x] = v;
    __syncthreads();
    for (int off = 1; off < 1024; off <<= 1) {
        int t = (threadIdx.x >= (unsigned)off) ? tmp[threadIdx.x - off] : 0;
        __syncthreads();
        tmp[threadIdx.x] += t;
        __syncthreads();
    }
    if ((int)threadIdx.x < nb) bsum[threadIdx.x] = tmp[threadIdx.x] - v;  // exclusive
}

__global__ void scan_add(int* __restrict__ start, const int* __restrict__ bsum,
                         int N, int E) {
    int i = blockIdx.x * SCAN_B + threadIdx.x;
    if (i < N) start[i] += bsum[i / SCAN_B];
    if (i == 0) start[N] = E;
}

// ---------------- CSR fill: eg[pos] = (src, norm) grouped by target ----------------
__global__ void fill_kernel(const int* __restrict__ row, const int* __restrict__ col,
                            const float* __restrict__ dis,
                            const int* __restrict__ start, int* __restrict__ cursor,
                            int2* __restrict__ eg, int E) {
    int e = blockIdx.x * blockDim.x + threadIdx.x;
    if (e < E) {
        int r = row[e], c = col[e];
        int pos = start[c] + atomicAdd(&cursor[c], 1);
        int2 v;
        v.x = r;
        v.y = __float_as_int(dis[r] * dis[c]);
        eg[pos] = v;
    }
}

// ---------------- pull-style propagate: one wave per node, lane d = dim d -------
// accB[n] = sum_{j in csr[n]} accA[src_j] * norm_j ; out = (out + accB) * scale
__global__ void gather_kernel(const int2* __restrict__ eg, const int* __restrict__ start,
                              const float* __restrict__ accA, float* __restrict__ accB,
                              float* __restrict__ out, float scale, int N) {
    int wave = blockIdx.x * (blockDim.x >> 6) + (threadIdx.x >> 6);
    int d = threadIdx.x & 63;
    if (wave >= N) return;
    int s = start[wave];
    int e = start[wave + 1];
    float sum = 0.0f;
    int j = s;
    for (; j + 1 < e; j += 2) {          // unroll 2 -> two outstanding gathers
        int2 e0 = eg[j];
        int2 e1 = eg[j + 1];
        float v0 = accA[(long long)e0.x * EMB + d];
        float v1 = accA[(long long)e1.x * EMB + d];
        sum += v0 * __int_as_float(e0.y);
        sum += v1 * __int_as_float(e1.y);
    }
    if (j < e) {
        int2 e0 = eg[j];
        sum += accA[(long long)e0.x * EMB + d] * __int_as_float(e0.y);
    }
    long long o = (long long)wave * EMB + d;
    accB[o] = sum;
    out[o] = (out[o] + sum) * scale;
}

extern "C" void kernel_launch(void* const* d_in, const int* in_sizes, int n_in,
                              void* d_out, int out_size, void* d_ws, size_t ws_size,
                              hipStream_t stream) {
    const int*   edge = (const int*)d_in[0];    // [2, E]: row then col
    const float* ue   = (const float*)d_in[2];
    const float* me   = (const float*)d_in[3];
    float*       out  = (float*)d_out;

    const int E        = in_sizes[0] / 2;
    const int n_users  = in_sizes[2] / EMB;
    const int n_movies = in_sizes[3] / EMB;
    const int N        = n_users + n_movies;
    const int* row = edge;
    const int* col = edge + E;

    // workspace layout
    char* ws = (char*)d_ws;
    auto align_up = [](size_t v) { return (v + 255) & ~(size_t)255; };
    int*   deg    = (int*)ws;   ws += align_up((size_t)N * sizeof(int));
    float* dis    = (float*)ws; ws += align_up((size_t)N * sizeof(float));
    int*   start  = (int*)ws;   ws += align_up((size_t)(N + 1) * sizeof(int));
    int*   cursor = (int*)ws;   ws += align_up((size_t)N * sizeof(int));
    int*   bsum   = (int*)ws;   ws += align_up((size_t)2048 * sizeof(int));
    int2*  eg     = (int2*)ws;  ws += align_up((size_t)E * sizeof(int2));
    float* accA   = (float*)ws; ws += align_up((size_t)N * EMB * sizeof(float));
    float* accB   = (float*)ws; ws += align_up((size_t)N * EMB * sizeof(float));

    const long long total_elems = (long long)N * EMB;
    const long long user_elems  = (long long)n_users * EMB;
    const int nb = (N + SCAN_B - 1) / SCAN_B;   // 586 <= 1024

    // degree + normalization
    hipMemsetAsync(deg, 0, (size_t)N * sizeof(int), stream);
    hipMemsetAsync(cursor, 0, (size_t)N * sizeof(int), stream);
    deg_kernel<<<(E + 255) / 256, 256, 0, stream>>>(col, deg, E);
    dis_kernel<<<(N + 255) / 256, 256, 0, stream>>>(deg, dis, N);

    // CSR: start = exclusive_scan(deg); eg grouped by col
    scan_block<<<nb, SCAN_B, 0, stream>>>(deg, start, bsum, N);
    scan_partials<<<1, 1024, 0, stream>>>(bsum, nb);
    scan_add<<<nb, SCAN_B, 0, stream>>>(start, bsum, N, E);
    fill_kernel<<<(E + 255) / 256, 256, 0, stream>>>(row, col, dis, start, cursor, eg, E);

    // acc0 = x, total = x
    init_kernel<<<(int)((total_elems + 255) / 256), 256, 0, stream>>>(
        ue, me, accA, out, user_elems, total_elems);

    // 3 propagation layers (atomic-free pull)
    const int waves_per_block = 4;   // 256 threads
    const int gblocks = (N + waves_per_block - 1) / waves_per_block;
    for (int l = 0; l < NLAYERS; ++l) {
        float scale = (l == NLAYERS - 1) ? 1.0f / (NLAYERS + 1) : 1.0f;
        gather_kernel<<<gblocks, 256, 0, stream>>>(eg, start, accA, accB, out, scale, N);
        float* t = accA; accA = accB; accB = t;
    }
}

// Round 3
// 1148.708 us; speedup vs baseline: 3.1597x; 1.2541x over previous
//
#include <hip/hip_runtime.h>

typedef _Float16 half_t;

#define EMB 64
#define NLAYERS 3
#define SCAN_B 256

// ---------------- degree: deg[col[e]] += 1 ----------------
__global__ void deg_kernel(const int* __restrict__ col, int* __restrict__ deg, int E) {
    int gid = blockIdx.x * blockDim.x + threadIdx.x;
    if (gid < E) atomicAdd(&deg[col[gid]], 1);
}

// ---------------- dis[i] = deg>0 ? rsqrt(deg) : 0 ----------------
__global__ void dis_kernel(const int* __restrict__ deg, float* __restrict__ dis, int N) {
    int gid = blockIdx.x * blockDim.x + threadIdx.x;
    if (gid < N) {
        int d = deg[gid];
        dis[gid] = (d > 0) ? rsqrtf((float)d) : 0.0f;
    }
}

// ---------------- init: out = x (fp32); acc0 = x (fp16) ----------------
__global__ void init_kernel(const float* __restrict__ ue, const float* __restrict__ me,
                            half_t* __restrict__ acc, float* __restrict__ out,
                            long long n_user_elems, long long total_elems) {
    long long gid = (long long)blockIdx.x * blockDim.x + threadIdx.x;
    if (gid < total_elems) {
        float v = (gid < n_user_elems) ? ue[gid] : me[gid - n_user_elems];
        acc[gid] = (half_t)v;
        out[gid] = v;
    }
}

// ---------------- CSR build: block-level exclusive scan of deg ----------------
__global__ void scan_block(const int* __restrict__ deg, int* __restrict__ start,
                           int* __restrict__ bsum, int N) {
    __shared__ int tmp[SCAN_B];
    int i = blockIdx.x * SCAN_B + threadIdx.x;
    int v = (i < N) ? deg[i] : 0;
    tmp[threadIdx.x] = v;
    __syncthreads();
    for (int off = 1; off < SCAN_B; off <<= 1) {
        int t = (threadIdx.x >= off) ? tmp[threadIdx.x - off] : 0;
        __syncthreads();
        tmp[threadIdx.x] += t;
        __syncthreads();
    }
    if (i < N) start[i] = tmp[threadIdx.x] - v;  // exclusive within block
    if (threadIdx.x == SCAN_B - 1) bsum[blockIdx.x] = tmp[threadIdx.x];
}

__global__ void scan_partials(int* __restrict__ bsum, int nb) {
    __shared__ int tmp[1024];
    int v = ((int)threadIdx.x < nb) ? bsum[threadIdx.x] : 0;
    tmp[threadIdx.x] = v;
    __syncthreads();
    for (int off = 1; off < 1024; off <<= 1) {
        int t = (threadIdx.x >= (unsigned)off) ? tmp[threadIdx.x - off] : 0;
        __syncthreads();
        tmp[threadIdx.x] += t;
        __syncthreads();
    }
    if ((int)threadIdx.x < nb) bsum[threadIdx.x] = tmp[threadIdx.x] - v;  // exclusive
}

__global__ void scan_add(int* __restrict__ start, const int* __restrict__ bsum,
                         int N, int E) {
    int i = blockIdx.x * SCAN_B + threadIdx.x;
    if (i < N) start[i] += bsum[i / SCAN_B];
    if (i == 0) start[N] = E;
}

// ---------------- CSR fill: eg[pos] = (src, norm) grouped by target ----------------
__global__ void fill_kernel(const int* __restrict__ row, const int* __restrict__ col,
                            const float* __restrict__ dis,
                            const int* __restrict__ start, int* __restrict__ cursor,
                            int2* __restrict__ eg, int E) {
    int e = blockIdx.x * blockDim.x + threadIdx.x;
    if (e < E) {
        int r = row[e], c = col[e];
        int pos = start[c] + atomicAdd(&cursor[c], 1);
        int2 v;
        v.x = r;
        v.y = __float_as_int(dis[r] * dis[c]);
        eg[pos] = v;
    }
}

// ---------------- pull-style propagate: one wave per node, lane d = dim d -------
// accB[n] = sum_{j in csr[n]} accA[src_j] * norm_j ; out = (out + accB) * scale
template <bool LAST>
__global__ void gather_kernel(const int2* __restrict__ eg, const int* __restrict__ start,
                              const half_t* __restrict__ accA, half_t* __restrict__ accB,
                              float* __restrict__ out, float scale, int N) {
    int wave = blockIdx.x * (blockDim.x >> 6) + (threadIdx.x >> 6);
    int d = threadIdx.x & 63;
    if (wave >= N) return;
    int s = start[wave];
    int e = start[wave + 1];
    float sum = 0.0f;
    int j = s;
    // unroll 4: four outstanding random-row gathers per wave
    for (; j + 3 < e; j += 4) {
        int2 e0 = eg[j];
        int2 e1 = eg[j + 1];
        int2 e2 = eg[j + 2];
        int2 e3 = eg[j + 3];
        float v0 = (float)accA[(long long)e0.x * EMB + d];
        float v1 = (float)accA[(long long)e1.x * EMB + d];
        float v2 = (float)accA[(long long)e2.x * EMB + d];
        float v3 = (float)accA[(long long)e3.x * EMB + d];
        sum += v0 * __int_as_float(e0.y);
        sum += v1 * __int_as_float(e1.y);
        sum += v2 * __int_as_float(e2.y);
        sum += v3 * __int_as_float(e3.y);
    }
    for (; j < e; ++j) {
        int2 e0 = eg[j];
        sum += (float)accA[(long long)e0.x * EMB + d] * __int_as_float(e0.y);
    }
    long long o = (long long)wave * EMB + d;
    if (!LAST) accB[o] = (half_t)sum;
    out[o] = (out[o] + sum) * scale;
}

extern "C" void kernel_launch(void* const* d_in, const int* in_sizes, int n_in,
                              void* d_out, int out_size, void* d_ws, size_t ws_size,
                              hipStream_t stream) {
    const int*   edge = (const int*)d_in[0];    // [2, E]: row then col
    const float* ue   = (const float*)d_in[2];
    const float* me   = (const float*)d_in[3];
    float*       out  = (float*)d_out;

    const int E        = in_sizes[0] / 2;
    const int n_users  = in_sizes[2] / EMB;
    const int n_movies = in_sizes[3] / EMB;
    const int N        = n_users + n_movies;
    const int* row = edge;
    const int* col = edge + E;

    // workspace layout
    char* ws = (char*)d_ws;
    auto align_up = [](size_t v) { return (v + 255) & ~(size_t)255; };
    int*    deg    = (int*)ws;    ws += align_up((size_t)N * sizeof(int));
    float*  dis    = (float*)ws;  ws += align_up((size_t)N * sizeof(float));
    int*    start  = (int*)ws;    ws += align_up((size_t)(N + 1) * sizeof(int));
    int*    cursor = (int*)ws;    ws += align_up((size_t)N * sizeof(int));
    int*    bsum   = (int*)ws;    ws += align_up((size_t)2048 * sizeof(int));
    int2*   eg     = (int2*)ws;   ws += align_up((size_t)E * sizeof(int2));
    half_t* accA   = (half_t*)ws; ws += align_up((size_t)N * EMB * sizeof(half_t));
    half_t* accB   = (half_t*)ws; ws += align_up((size_t)N * EMB * sizeof(half_t));

    const long long total_elems = (long long)N * EMB;
    const long long user_elems  = (long long)n_users * EMB;
    const int nb = (N + SCAN_B - 1) / SCAN_B;   // 586 <= 1024

    // degree + normalization
    hipMemsetAsync(deg, 0, (size_t)N * sizeof(int), stream);
    hipMemsetAsync(cursor, 0, (size_t)N * sizeof(int), stream);
    deg_kernel<<<(E + 255) / 256, 256, 0, stream>>>(col, deg, E);
    dis_kernel<<<(N + 255) / 256, 256, 0, stream>>>(deg, dis, N);

    // CSR: start = exclusive_scan(deg); eg grouped by col
    scan_block<<<nb, SCAN_B, 0, stream>>>(deg, start, bsum, N);
    scan_partials<<<1, 1024, 0, stream>>>(bsum, nb);
    scan_add<<<nb, SCAN_B, 0, stream>>>(start, bsum, N, E);
    fill_kernel<<<(E + 255) / 256, 256, 0, stream>>>(row, col, dis, start, cursor, eg, E);

    // out = x, acc0 = fp16(x)
    init_kernel<<<(int)((total_elems + 255) / 256), 256, 0, stream>>>(
        ue, me, accA, out, user_elems, total_elems);

    // 3 propagation layers (atomic-free pull, fp16 storage, fp32 accumulate)
    const int waves_per_block = 4;   // 256 threads
    const int gblocks = (N + waves_per_block - 1) / waves_per_block;
    gather_kernel<false><<<gblocks, 256, 0, stream>>>(eg, start, accA, accB, out, 1.0f, N);
    gather_kernel<false><<<gblocks, 256, 0, stream>>>(eg, start, accB, accA, out, 1.0f, N);
    gather_kernel<true><<<gblocks, 256, 0, stream>>>(eg, start, accA, accB, out,
                                                     1.0f / (NLAYERS + 1), N);
}